// Round 4
// baseline (193.702 us; speedup 1.0000x reference)
//
#include <hip/hip_runtime.h>
#include <hip/hip_bf16.h>

typedef __attribute__((ext_vector_type(8))) short bf16x8;
typedef __attribute__((ext_vector_type(4))) short s16x4;
typedef __attribute__((ext_vector_type(4))) float f32x4;

#define NTOK 49

__device__ __forceinline__ short f2b(float v) {
    __hip_bfloat16 b = __float2bfloat16(v);
    return *reinterpret_cast<short*>(&b);
}

__device__ __forceinline__ s16x4 shfl64(s16x4 v, int src) {
    long long x = *reinterpret_cast<long long*>(&v);
    x = __shfl(x, src, 64);
    return *reinterpret_cast<s16x4*>(&x);
}

__device__ __forceinline__ bf16x8 cat8(s16x4 lo, s16x4 hi) {
    bf16x8 r;
    r[0]=lo[0]; r[1]=lo[1]; r[2]=lo[2]; r[3]=lo[3];
    r[4]=hi[0]; r[5]=hi[1]; r[6]=hi[2]; r[7]=hi[3];
    return r;
}

// region id: mask[w][i][j]==0 iff rid(i)==rid(j); slices [0,49)[49,53)[53,56)
__device__ __forceinline__ int rid_of(int t, int wh, int ww) {
    int i = t / 7;
    int j = t - 7 * i;
    int rh = (wh == 7) ? ((i < 4) ? 1 : 2) : 0;
    int rw = (ww == 7) ? ((j < 4) ? 1 : 2) : 0;
    return rh * 3 + rw;
}

__global__ void prep_kernel(const float* __restrict__ qkv_w,
                            const float* __restrict__ proj_w,
                            const float* __restrict__ rel_tab,
                            const int*   __restrict__ rel_idx,
                            short* __restrict__ wqkv_t,
                            short* __restrict__ wproj_t,
                            float* __restrict__ bmp) {
    int i = blockIdx.x * 256 + threadIdx.x;
    if (i < 384 * 128) {               // wqkv_t[n][k] = qkv_w[k][n]
        int n = i >> 7, k = i & 127;
        wqkv_t[i] = f2b(qkv_w[k * 384 + n]);
        return;
    }
    int j = i - 384 * 128;
    if (j < 128 * 128) {               // wproj_t[n][k] = proj_w[k][n]
        int n = j >> 7, k = j & 127;
        wproj_t[j] = f2b(proj_w[k * 128 + n]);
        return;
    }
    int l = j - 128 * 128;
    if (l < 4 * NTOK * 64) {           // bmp[h][q][k64] = tab[rel_idx[q][k]][h], pad 0
        int h = l / (NTOK * 64);
        int rem = l - h * (NTOK * 64);
        int q = rem >> 6, kk = rem & 63;
        bmp[l] = (kk < NTOK) ? rel_tab[rel_idx[q * NTOK + kk] * 4 + h] : 0.0f;
    }
}

// LDS (shorts), 24896 total = 49792 B -> 3 blocks/CU:
//  RV  [0,9216):    X [49][136] (ph0-1) -> vbt 4x[32][72] (ph1e-ph3) -> ob [49][136] (ph3e-ph4)
//  RQK [9216,24896): head h at 9216+h*3920: q [49][40], k at +1960
__launch_bounds__(512, 6)
__global__ void swin_fused(const float* __restrict__ x,
                           const short* __restrict__ wqkv_t,
                           const float* __restrict__ qkv_b,
                           const short* __restrict__ wproj_t,
                           const float* __restrict__ proj_b,
                           const float* __restrict__ bmp,
                           float* __restrict__ out) {
    __shared__ short sm[24896];

    const int b   = blockIdx.x;
    const int tid = threadIdx.x;
    const int wv  = tid >> 6;
    const int ln  = tid & 63;
    const int g   = ln >> 4;
    const int c   = ln & 15;
    const int h    = wv >> 1;
    const int half = wv & 1;

    short* qbh = sm + 9216 + h * 3920;   // [49][40]
    short* kbh = qbh + 1960;             // [49][40]
    short* vbt = sm + h * 2304;          // [32][72] (valid after B1.5)

    // ---------- phase 0: X (49x128 f32) -> bf16 LDS; all loads issued first ----------
    {
        const f32x4* xp4 = (const f32x4*)(x + (size_t)b * 6272);
        f32x4 v0 = xp4[tid];
        f32x4 v1 = xp4[tid + 512];
        f32x4 v2 = xp4[tid + 1024];
        f32x4 v3;
        if (tid < 32) v3 = xp4[tid + 1536];
        #define XWR(IDX, V) { int row = (IDX) >> 5; int col = ((IDX) & 31) * 4; \
            s16x4 pk; pk[0]=f2b((V)[0]); pk[1]=f2b((V)[1]); pk[2]=f2b((V)[2]); pk[3]=f2b((V)[3]); \
            *(s16x4*)&sm[row * 136 + col] = pk; }
        XWR(tid, v0) XWR(tid + 512, v1) XWR(tid + 1024, v2)
        if (tid < 32) XWR(tid + 1536, v3)
        #undef XWR
    }
    __syncthreads();   // B1

    const int cq = 32 * h + 16 * half;   // this wave's 16-channel base within q/k/v

    // ---------- phase 1a: Q,K channels [cq,cq+16) over 64 toks ----------
    {
        f32x4 accq[4], acck[4];
        #pragma unroll
        for (int nt = 0; nt < 4; ++nt) { accq[nt] = (f32x4){0.f,0.f,0.f,0.f}; acck[nt] = (f32x4){0.f,0.f,0.f,0.f}; }
        #pragma unroll
        for (int kt = 0; kt < 4; ++kt) {
            bf16x8 awq = *(const bf16x8*)&wqkv_t[(cq + c) * 128 + 32*kt + 8*g];
            bf16x8 awk = *(const bf16x8*)&wqkv_t[(128 + cq + c) * 128 + 32*kt + 8*g];
            bf16x8 xv[4];
            #pragma unroll
            for (int nt = 0; nt < 4; ++nt) {
                int tok = 16*nt + c; if (tok > 48) tok = 48;
                xv[nt] = *(const bf16x8*)&sm[tok * 136 + 32*kt + 8*g];
            }
            #pragma unroll
            for (int nt = 0; nt < 4; ++nt) {
                accq[nt] = __builtin_amdgcn_mfma_f32_16x16x32_bf16(awq, xv[nt], accq[nt], 0, 0, 0);
                acck[nt] = __builtin_amdgcn_mfma_f32_16x16x32_bf16(awk, xv[nt], acck[nt], 0, 0, 0);
            }
        }
        const float qsc = 0.17677669529663687f;  // 32^-0.5 folded into q
        f32x4 bq4 = *(const f32x4*)&qkv_b[cq + 4*g];
        f32x4 bk4 = *(const f32x4*)&qkv_b[128 + cq + 4*g];
        #pragma unroll
        for (int nt = 0; nt < 4; ++nt) {
            int tok = 16*nt + c;
            if (tok >= NTOK) continue;
            s16x4 pq, pk2;
            #pragma unroll
            for (int r = 0; r < 4; ++r) {
                pq[r]  = f2b((accq[nt][r] + bq4[r]) * qsc);
                pk2[r] = f2b(acck[nt][r] + bk4[r]);
            }
            *(s16x4*)&qbh[tok * 40 + 16*half + 4*g] = pq;
            *(s16x4*)&kbh[tok * 40 + 16*half + 4*g] = pk2;
        }
    }

    // ---------- phase 1b: V channels; MFMAs read X, writes go to vbt after B1.5 ----------
    {
        f32x4 accv[4];
        #pragma unroll
        for (int nt = 0; nt < 4; ++nt) accv[nt] = (f32x4){0.f,0.f,0.f,0.f};
        #pragma unroll
        for (int kt = 0; kt < 4; ++kt) {
            bf16x8 awv = *(const bf16x8*)&wqkv_t[(256 + cq + c) * 128 + 32*kt + 8*g];
            bf16x8 xv[4];
            #pragma unroll
            for (int nt = 0; nt < 4; ++nt) {
                int tok = 16*nt + c; if (tok > 48) tok = 48;
                xv[nt] = *(const bf16x8*)&sm[tok * 136 + 32*kt + 8*g];
            }
            #pragma unroll
            for (int nt = 0; nt < 4; ++nt)
                accv[nt] = __builtin_amdgcn_mfma_f32_16x16x32_bf16(awv, xv[nt], accv[nt], 0, 0, 0);
        }
        __syncthreads();   // B1.5: all X reads done; RV region becomes vbt
        f32x4 bv4 = *(const f32x4*)&qkv_b[256 + cq + 4*g];
        const int d0 = 16*half + 4*g;
        #pragma unroll
        for (int nt = 0; nt < 4; ++nt) {
            int tok = 16*nt + c;
            if (tok >= NTOK) continue;
            vbt[(d0+0) * 72 + tok] = f2b(accv[nt][0] + bv4[0]);
            vbt[(d0+1) * 72 + tok] = f2b(accv[nt][1] + bv4[1]);
            vbt[(d0+2) * 72 + tok] = f2b(accv[nt][2] + bv4[2]);
            vbt[(d0+3) * 72 + tok] = f2b(accv[nt][3] + bv4[3]);
        }
        for (int i2 = ln; i2 < 16 * 15; i2 += 64) {   // zero toks 49..63
            int d = 16*half + i2 / 15;
            int t = 49 + i2 % 15;
            vbt[d * 72 + t] = 0;
        }
    }
    __syncthreads();   // B2: q,k,vbt ready

    // ---------- phase 2: S^T = K @ Q^T; softmax in-register; PV via shuffled P ----------
    const int ntq0 = 2 * half;
    {
        // bias prefetch (jj=0)
        int qtok0 = 16*ntq0 + c;  int q0c = qtok0 > 48 ? 48 : qtok0;
        const float* bp0 = bmp + ((size_t)h * NTOK + q0c) * 64;
        f32x4 bias0[4];
        #pragma unroll
        for (int mt = 0; mt < 4; ++mt) bias0[mt] = *(const f32x4*)&bp0[16*mt + 4*g];

        f32x4 sA[4][2];
        #pragma unroll
        for (int mt = 0; mt < 4; ++mt) { sA[mt][0] = (f32x4){0.f,0.f,0.f,0.f}; sA[mt][1] = (f32x4){0.f,0.f,0.f,0.f}; }
        bf16x8 ak[4];
        #pragma unroll
        for (int mt = 0; mt < 4; ++mt) {
            int kt2 = 16*mt + c; if (kt2 > 48) kt2 = 48;
            ak[mt] = *(const bf16x8*)&kbh[kt2 * 40 + 8*g];
        }
        #pragma unroll
        for (int jj = 0; jj < 2; ++jj) {
            int qt = 16*(ntq0+jj) + c; if (qt > 48) qt = 48;
            bf16x8 bq = *(const bf16x8*)&qbh[qt * 40 + 8*g];
            #pragma unroll
            for (int mt = 0; mt < 4; ++mt)
                sA[mt][jj] = __builtin_amdgcn_mfma_f32_16x16x32_bf16(ak[mt], bq, sA[mt][jj], 0, 0, 0);
        }

        // bias prefetch (jj=1)
        int qtok1 = 16*(ntq0+1) + c;  int q1c = qtok1 > 48 ? 48 : qtok1;
        const float* bp1 = bmp + ((size_t)h * NTOK + q1c) * 64;
        f32x4 bias1[4];
        #pragma unroll
        for (int mt = 0; mt < 4; ++mt) bias1[mt] = *(const f32x4*)&bp1[16*mt + 4*g];

        // V fragments (vbt ready since B2)
        bf16x8 av[2][2];
        #pragma unroll
        for (int kt = 0; kt < 2; ++kt)
            #pragma unroll
            for (int mt = 0; mt < 2; ++mt)
                av[kt][mt] = *(const bf16x8*)&vbt[(16*mt + c) * 72 + 32*kt + 8*g];

        const int wh = (b >> 3) & 7, ww = b & 7;
        const bool wmask = (wh == 7) || (ww == 7);
        int ridk[16];
        if (wmask) {
            #pragma unroll
            for (int mt = 0; mt < 4; ++mt)
                #pragma unroll
                for (int r = 0; r < 4; ++r) {
                    int ktok = 16*mt + 4*g + r;
                    ridk[4*mt+r] = rid_of(ktok < NTOK ? ktok : 48, wh, ww);
                }
        }

        f32x4 o[2][2];
        o[0][0]=(f32x4){0.f,0.f,0.f,0.f}; o[0][1]=(f32x4){0.f,0.f,0.f,0.f};
        o[1][0]=(f32x4){0.f,0.f,0.f,0.f}; o[1][1]=(f32x4){0.f,0.f,0.f,0.f};
        const int srcL = 32*(g & 1) + c;
        const int srcH = srcL + 16;

        #pragma unroll
        for (int jj = 0; jj < 2; ++jj) {
            int qtok = 16*(ntq0+jj) + c;
            int qtokc = qtok > 48 ? 48 : qtok;
            int ridq = wmask ? rid_of(qtokc, wh, ww) : 0;
            const f32x4* bias = jj ? bias1 : bias0;
            float e[16];
            float mx = -1e30f;
            #pragma unroll
            for (int mt = 0; mt < 4; ++mt) {
                #pragma unroll
                for (int r = 0; r < 4; ++r) {
                    int ktok = 16*mt + 4*g + r;
                    float v = sA[mt][jj][r] + bias[mt][r];
                    bool ok = (ktok < NTOK) && (!wmask || (ridk[4*mt+r] == ridq));
                    v = ok ? v : -1e30f;
                    e[4*mt+r] = v;
                    mx = fmaxf(mx, v);
                }
            }
            mx = fmaxf(mx, __shfl_xor(mx, 16, 64));
            mx = fmaxf(mx, __shfl_xor(mx, 32, 64));
            float s = 0.f;
            #pragma unroll
            for (int ii = 0; ii < 16; ++ii) { float ev = __expf(e[ii] - mx); e[ii] = ev; s += ev; }
            s += __shfl_xor(s, 16, 64);
            s += __shfl_xor(s, 32, 64);
            float rs = 1.0f / s;
            s16x4 pk[4];
            #pragma unroll
            for (int m = 0; m < 4; ++m) {
                pk[m][0] = f2b(e[4*m+0] * rs); pk[m][1] = f2b(e[4*m+1] * rs);
                pk[m][2] = f2b(e[4*m+2] * rs); pk[m][3] = f2b(e[4*m+3] * rs);
            }
            // build PV B-fragments: B[i] = P[ktok=32kt+8g+i] for qtok col c
            #pragma unroll
            for (int kt = 0; kt < 2; ++kt) {
                s16x4 aL  = shfl64(pk[2*kt],     srcL);
                s16x4 aLb = shfl64(pk[2*kt + 1], srcL);
                s16x4 aH  = shfl64(pk[2*kt],     srcH);
                s16x4 aHb = shfl64(pk[2*kt + 1], srcH);
                bf16x8 B = cat8((g < 2) ? aL : aLb, (g < 2) ? aH : aHb);
                #pragma unroll
                for (int mt = 0; mt < 2; ++mt)
                    o[mt][jj] = __builtin_amdgcn_mfma_f32_16x16x32_bf16(av[kt][mt], B, o[mt][jj], 0, 0, 0);
            }
        }
        __syncthreads();   // B3: all PV reads of vbt done; RV becomes ob
        #pragma unroll
        for (int jj = 0; jj < 2; ++jj) {
            int qtok = 16*(ntq0+jj) + c;
            if (qtok >= NTOK) continue;
            #pragma unroll
            for (int mt = 0; mt < 2; ++mt) {
                s16x4 pko;
                pko[0] = f2b(o[mt][jj][0]); pko[1] = f2b(o[mt][jj][1]);
                pko[2] = f2b(o[mt][jj][2]); pko[3] = f2b(o[mt][jj][3]);
                *(s16x4*)&sm[qtok * 136 + 32*h + 16*mt + 4*g] = pko;
            }
        }
    }
    __syncthreads();   // B4: ob complete

    // ---------- phase 4: Y^T = Wp^T(128x128) @ O^T(128x49pad) ----------
    {
        const int chb = 16 * wv;
        f32x4 po[4];
        #pragma unroll
        for (int j = 0; j < 4; ++j) po[j] = (f32x4){0.f,0.f,0.f,0.f};
        #pragma unroll
        for (int kt = 0; kt < 4; ++kt) {
            bf16x8 aw = *(const bf16x8*)&wproj_t[(chb + c) * 128 + 32*kt + 8*g];
            #pragma unroll
            for (int j = 0; j < 4; ++j) {
                int qt = 16*j + c; if (qt > 48) qt = 48;
                bf16x8 bo = *(const bf16x8*)&sm[qt * 136 + 32*kt + 8*g];
                po[j] = __builtin_amdgcn_mfma_f32_16x16x32_bf16(aw, bo, po[j], 0, 0, 0);
            }
        }
        f32x4 pb4 = *(const f32x4*)&proj_b[chb + 4*g];
        float* op = out + (size_t)b * 6272;
        #pragma unroll
        for (int j = 0; j < 4; ++j) {
            int qtok = 16*j + c;
            if (qtok >= NTOK) continue;
            f32x4 w;
            w[0] = po[j][0] + pb4[0]; w[1] = po[j][1] + pb4[1];
            w[2] = po[j][2] + pb4[2]; w[3] = po[j][3] + pb4[3];
            *(f32x4*)&op[qtok * 128 + chb + 4*g] = w;
        }
    }
}

extern "C" void kernel_launch(void* const* d_in, const int* in_sizes, int n_in,
                              void* d_out, int out_size, void* d_ws, size_t ws_size,
                              hipStream_t stream) {
    const float* x       = (const float*)d_in[0];
    const float* qkv_w   = (const float*)d_in[1];
    const float* qkv_b   = (const float*)d_in[2];
    const float* proj_w  = (const float*)d_in[3];
    const float* proj_b  = (const float*)d_in[4];
    const float* rel_tab = (const float*)d_in[5];
    const int*   rel_idx = (const int*)d_in[7];

    char* ws = (char*)d_ws;
    short* wqkv_t  = (short*)ws;                        // 98304 B
    short* wproj_t = (short*)(ws + 98304);              // 32768 B
    float* bmp     = (float*)(ws + 98304 + 32768);      // 50176 B

    int total = 384*128 + 128*128 + 4*NTOK*64;
    prep_kernel<<<(total + 255) / 256, 256, 0, stream>>>(qkv_w, proj_w, rel_tab, rel_idx,
                                                         wqkv_t, wproj_t, bmp);

    int B_ = in_sizes[0] / (NTOK * 128);                // 4096
    swin_fused<<<B_, 512, 0, stream>>>(x, wqkv_t, qkv_b, wproj_t, proj_b, bmp,
                                       (float*)d_out);
}